// Round 17
// baseline (230.370 us; speedup 1.0000x reference)
//
#include <hip/hip_runtime.h>
#include <hip/hip_bf16.h>
#include <hip/hip_fp16.h>

// Problem constants (match reference)
#define N_ATOMS 20000
#define N_EDGES 400000
#define NCH 4
#define F_IN 128
#define S_OUT 32

// ---------- helpers ----------
__device__ __forceinline__ float silu_f(float v) { return v / (1.f + __expf(-v)); }

typedef _Float16 fh2 __attribute__((ext_vector_type(2)));

// 8-element fp16 dot with f32 accumulate (v_dot2_f32_f16 x4)
__device__ __forceinline__ float dot8(float4 a, float4 b, float c) {
#if __has_builtin(__builtin_amdgcn_fdot2)
    union { float4 f; fh2 h[4]; } ua, ub;
    ua.f = a; ub.f = b;
    c = __builtin_amdgcn_fdot2(ua.h[0], ub.h[0], c, false);
    c = __builtin_amdgcn_fdot2(ua.h[1], ub.h[1], c, false);
    c = __builtin_amdgcn_fdot2(ua.h[2], ub.h[2], c, false);
    c = __builtin_amdgcn_fdot2(ua.h[3], ub.h[3], c, false);
#else
    union { float4 f; __half2 h[4]; } ua, ub;
    ua.f = a; ub.f = b;
#pragma unroll
    for (int t = 0; t < 4; ++t) {
        float2 fa = __half22float2(ua.h[t]);
        float2 fb = __half22float2(ub.h[t]);
        c = fmaf(fa.x, fb.x, c);
        c = fmaf(fa.y, fb.y, c);
    }
#endif
    return c;
}

__device__ __forceinline__ int wave_iscan(int v, int l) {
#pragma unroll
    for (int off = 1; off < 64; off <<= 1) {
        int t = __shfl_up(v, off);
        if (l >= off) v += t;
    }
    return v;
}

// ---------- fill ----------
__global__ void fill_kernel(float* __restrict__ p, int n, float v) {
    int i = blockIdx.x * blockDim.x + threadIdx.x;
    int stride = gridDim.x * blockDim.x;
    for (; i < n; i += stride) p[i] = v;
}

// ---------- CSR build: histogram -> hierarchical scan -> scatter ----------
__global__ void hist_kernel(const int* __restrict__ ei, int* __restrict__ cnt, int E) {
    int e = blockIdx.x * 256 + threadIdx.x;
    if (e < E) atomicAdd(&cnt[ei[E + e]], 1);
}

__global__ __launch_bounds__(256) void scan_l1_kernel(const int* __restrict__ cnt,
                                                      int* __restrict__ rowp,
                                                      int* __restrict__ bsum, int n) {
    int i = blockIdx.x * 256 + threadIdx.x;
    int l = threadIdx.x & 63, w = threadIdx.x >> 6;
    int v = (i < n) ? cnt[i] : 0;
    int incl = wave_iscan(v, l);
    __shared__ int wsum[4];
    if (l == 63) wsum[w] = incl;
    __syncthreads();
    int add = 0;
#pragma unroll
    for (int j = 0; j < 4; ++j) add += (j < w) ? wsum[j] : 0;
    if (i < n) rowp[i] = add + incl - v;
    if (threadIdx.x == 255) bsum[blockIdx.x] = add + incl;
}

__global__ __launch_bounds__(256) void scan_l2_kernel(const int* __restrict__ bsum,
                                                      int* __restrict__ boff,
                                                      int* __restrict__ rowp_n, int nb,
                                                      float* __restrict__ out_zero) {
    int i = threadIdx.x;
    if (i < S_OUT) out_zero[i] = 0.f;  // fused energies zero-init
    int l = i & 63, w = i >> 6;
    int v = (i < nb) ? bsum[i] : 0;
    int incl = wave_iscan(v, l);
    __shared__ int wsum[4];
    if (l == 63) wsum[w] = incl;
    __syncthreads();
    int add = 0;
#pragma unroll
    for (int j = 0; j < 4; ++j) add += (j < w) ? wsum[j] : 0;
    if (i < nb) boff[i] = add + incl - v;
    if (i == nb - 1) *rowp_n = add + incl;
}

__global__ __launch_bounds__(256) void scan_l3_kernel(int* __restrict__ rowp,
                                                      const int* __restrict__ boff, int n) {
    int i = blockIdx.x * 256 + threadIdx.x;
    if (i < n) rowp[i] += boff[blockIdx.x];
}

__global__ void scatter_kernel(const int* __restrict__ ei, const int* __restrict__ rowp,
                               int* __restrict__ fill, int* __restrict__ csr_src, int E) {
    int e = blockIdx.x * 256 + threadIdx.x;
    if (e < E) {
        int d = ei[E + e];
        int pos = rowp[d] + atomicAdd(&fill[d], 1);
        csr_src[pos] = ei[e];
    }
}

// ---------- projection: 4-node x 4-output register tile, fp16 LDS + fdot2 ----------
// block = 64 nodes, c = blockIdx.y. thread (np=t>>4 -> 4 nodes, oq=t&15 -> 4 outs).
// Per octet: 4 weight b128 + 4 input b128 (16-lane broadcast) -> 128 MACs (8 LDS/128).
template <int FIN, int IN_STRIDE, bool IN_HALF, bool LN, bool ATT, bool SILU_OUT, bool OUT_HALF>
__global__ __launch_bounds__(256) void proj_kernel(const void* __restrict__ inv,
                                                   const float* __restrict__ gamma,
                                                   const float* __restrict__ beta,
                                                   const float* __restrict__ W,
                                                   const float* __restrict__ a_src,
                                                   const float* __restrict__ a_dst,
                                                   void* __restrict__ outv,
                                                   float* __restrict__ es,
                                                   float* __restrict__ ed) {
    constexpr int OCT = FIN / 8;      // octets per row
    constexpr int OM = OCT - 1;
    constexpr int WSH = FIN + 8;      // halves stride (16B-aligned rows)
    __shared__ __half Wt[64 * WSH];   // [o][store-swizzled k]
    __shared__ __half inl[64 * WSH];  // [node][k] linear
    const int tid = threadIdx.x;
    const int c = blockIdx.y;
    const int n0 = blockIdx.x * 64;
    const int np = tid >> 4;          // node quad 0..15
    const int oq = tid & 15;          // output quad 0..15

    // stage W (pack k-pairs to half2; octet store-swizzle by o>>2)
    const float* __restrict__ Wc = W + c * (FIN * 64);
    for (int i = tid; i < (FIN / 2) * 64; i += 256) {
        int kp = i >> 6, oo = i & 63;
        int k = kp * 2;
        float w0 = Wc[(size_t)k * 64 + oo];
        float w1 = Wc[(size_t)(k + 1) * 64 + oo];
        int pos = ((((k >> 3) ^ (oo >> 2)) & OM) << 3) | (k & 7);
        *(__half2*)(&Wt[oo * WSH + pos]) = __floats2half2_rn(w0, w1);
    }
    // stage 64 input rows (node index clamped; stores guarded later)
    if (IN_HALF) {
        const __half* __restrict__ inh = (const __half*)inv;
        for (int i = tid; i < 64 * FIN; i += 256) {
            int nl = i / FIN, k = i & (FIN - 1);
            int node = min(n0 + nl, N_ATOMS - 1);
            inl[nl * WSH + k] = inh[(size_t)node * IN_STRIDE + c * FIN + k];
        }
    } else {
        const float* __restrict__ inf = (const float*)inv;
        for (int i = tid; i < 64 * FIN; i += 256) {
            int nl = i / FIN, k = i & (FIN - 1);
            int node = min(n0 + nl, N_ATOMS - 1);
            inl[nl * WSH + k] = __float2half(inf[(size_t)node * IN_STRIDE + c * FIN + k]);
        }
    }
    __syncthreads();

    if (LN) {  // in-place LayerNorm per 128-row; wave w owns rows 16w..16w+15
        int l = tid & 63, w = tid >> 6;
        float gl0 = gamma[l], gl1 = gamma[l + 64];
        float bl0 = beta[l], bl1 = beta[l + 64];
#pragma unroll
        for (int r = 0; r < 16; ++r) {
            int row = w * 16 + r;
            float v0 = __half2float(inl[row * WSH + l]);
            float v1 = __half2float(inl[row * WSH + l + 64]);
            float s = v0 + v1, sq = v0 * v0 + v1 * v1;
#pragma unroll
            for (int off = 32; off; off >>= 1) {
                s += __shfl_xor(s, off);
                sq += __shfl_xor(sq, off);
            }
            float mu = s * (1.f / 128.f);
            float rs = rsqrtf(sq * (1.f / 128.f) - mu * mu + 1e-5f);
            inl[row * WSH + l]      = __float2half((v0 - mu) * rs * gl0 + bl0);
            inl[row * WSH + l + 64] = __float2half((v1 - mu) * rs * gl1 + bl1);
        }
        __syncthreads();
    }

    float acc[4][4];
#pragma unroll
    for (int i = 0; i < 4; ++i)
#pragma unroll
        for (int j = 0; j < 4; ++j) acc[i][j] = 0.f;

    const __half* ip = inl + (np * 4) * WSH;
    const __half* wp = Wt + (oq * 4) * WSH;

#pragma unroll 4
    for (int j = 0; j < OCT; ++j) {
        int sj = ((j ^ oq) & OM) << 3;             // store-swizzle inverse -> logical octet j
        float4 w0 = *(const float4*)(wp + sj);
        float4 w1 = *(const float4*)(wp + WSH + sj);
        float4 w2 = *(const float4*)(wp + 2 * WSH + sj);
        float4 w3 = *(const float4*)(wp + 3 * WSH + sj);
#pragma unroll
        for (int i = 0; i < 4; ++i) {
            float4 v = *(const float4*)(ip + i * WSH + (j << 3));  // 16-lane broadcast
            acc[i][0] = dot8(v, w0, acc[i][0]);
            acc[i][1] = dot8(v, w1, acc[i][1]);
            acc[i][2] = dot8(v, w2, acc[i][2]);
            acc[i][3] = dot8(v, w3, acc[i][3]);
        }
    }

#pragma unroll
    for (int i = 0; i < 4; ++i) {
        int node = n0 + np * 4 + i;
        bool valid = node < N_ATOMS;
        float o0 = acc[i][0], o1 = acc[i][1], o2 = acc[i][2], o3 = acc[i][3];
        if (SILU_OUT) { o0 = silu_f(o0); o1 = silu_f(o1); o2 = silu_f(o2); o3 = silu_f(o3); }
        if (valid) {
            if (OUT_HALF) {
                __half* outh = (__half*)outv;
                float2 st;
                __half2* sp = (__half2*)&st;
                sp[0] = __floats2half2_rn(o0, o1);
                sp[1] = __floats2half2_rn(o2, o3);
                *(float2*)(outh + (size_t)node * 256 + c * 64 + oq * 4) = st;
            } else {
                *(float4*)((float*)outv + (size_t)node * 256 + c * 64 + oq * 4) =
                    make_float4(o0, o1, o2, o3);
            }
        }
        if (ATT) {
            float4 av4 = *(const float4*)(a_src + c * 64 + oq * 4);
            float4 bv4 = *(const float4*)(a_dst + c * 64 + oq * 4);
            float ps = acc[i][0] * av4.x + acc[i][1] * av4.y + acc[i][2] * av4.z + acc[i][3] * av4.w;
            float pd = acc[i][0] * bv4.x + acc[i][1] * bv4.y + acc[i][2] * bv4.z + acc[i][3] * bv4.w;
#pragma unroll
            for (int off = 1; off < 16; off <<= 1) {
                ps += __shfl_xor(ps, off);
                pd += __shfl_xor(pd, off);
            }
            if (oq == 0 && valid) { es[node * NCH + c] = ps; ed[node * NCH + c] = pd; }
        }
    }
}

// ---------- fused GAT aggregation: ONE wave per dst, all 4 channels ----------
__global__ __launch_bounds__(256) void gat_gather_kernel(const int* __restrict__ rowp,
                                                         const int* __restrict__ csr_src,
                                                         const float* __restrict__ es,
                                                         const float* __restrict__ ed,
                                                         const __half* __restrict__ h,
                                                         __half* __restrict__ out) {
    int l = threadIdx.x & 63;
    int d = blockIdx.x * 4 + (threadIdx.x >> 6);
    int c = l >> 4, q = l & 15;
    int r0 = rowp[d], r1 = rowp[d + 1];
    float edc = ed[d * NCH + c];
    float m = -1e30f, den = 0.f;
    float a0 = 0.f, a1 = 0.f, a2 = 0.f, a3 = 0.f;
    int grp = l & 48;

    for (int base = r0; base < r1; base += 16) {
        int len = min(16, r1 - base);
        // phase A: lanes q = edge slots, per channel group
        float logit = -1e30f;
        int s = 0;
        if (q < len) {
            s = csr_src[base + q];
            float v = es[s * NCH + c] + edc;
            logit = v >= 0.f ? v : 0.2f * v;
        }
        float cm = logit;
#pragma unroll
        for (int off = 8; off; off >>= 1) cm = fmaxf(cm, __shfl_xor(cm, off));
        float nm = fmaxf(m, cm);
        float resc = __expf(m - nm);
        float ex = (q < len) ? __expf(logit - nm) : 0.f;
        float cs = ex;
#pragma unroll
        for (int off = 8; off; off >>= 1) cs += __shfl_xor(cs, off);
        den = den * resc + cs;
        a0 *= resc; a1 *= resc; a2 *= resc; a3 *= resc;
        m = nm;
        // phase B: per edge, one coalesced 512B row load; lane reads its 4 halves
        int e = 0;
        for (; e + 2 <= len; e += 2) {
            int s0 = __shfl(s, e);             // wave-uniform -> readlane
            int s1 = __shfl(s, e + 1);
            float x0 = __shfl(ex, grp | e);    // per-group broadcast (bpermute)
            float x1 = __shfl(ex, grp | (e + 1));
            float2 hv0 = *(const float2*)(h + (size_t)s0 * 256 + l * 4);
            float2 hv1 = *(const float2*)(h + (size_t)s1 * 256 + l * 4);
            __half2* hp0 = (__half2*)&hv0;
            __half2* hp1 = (__half2*)&hv1;
            float2 f00 = __half22float2(hp0[0]), f01 = __half22float2(hp0[1]);
            float2 f10 = __half22float2(hp1[0]), f11 = __half22float2(hp1[1]);
            a0 = fmaf(x0, f00.x, fmaf(x1, f10.x, a0));
            a1 = fmaf(x0, f00.y, fmaf(x1, f10.y, a1));
            a2 = fmaf(x0, f01.x, fmaf(x1, f11.x, a2));
            a3 = fmaf(x0, f01.y, fmaf(x1, f11.y, a3));
        }
        for (; e < len; ++e) {
            int se = __shfl(s, e);
            float xe = __shfl(ex, grp | e);
            float2 hv = *(const float2*)(h + (size_t)se * 256 + l * 4);
            __half2* hp = (__half2*)&hv;
            float2 f0 = __half22float2(hp[0]), f1 = __half22float2(hp[1]);
            a0 = fmaf(xe, f0.x, a0);
            a1 = fmaf(xe, f0.y, a1);
            a2 = fmaf(xe, f1.x, a2);
            a3 = fmaf(xe, f1.y, a3);
        }
    }
    float inv = 1.f / (den + 1e-16f);
    float2 st;
    __half2* sp = (__half2*)&st;
    sp[0] = __floats2half2_rn(silu_f(a0 * inv), silu_f(a1 * inv));
    sp[1] = __floats2half2_rn(silu_f(a2 * inv), silu_f(a3 * inv));
    *(float2*)(out + (size_t)d * 256 + l * 4) = st;
}

// ---------- MLP layers 2+3 (64->32->1, all channels) + energy reduction ----------
__global__ __launch_bounds__(256) void mlp23_kernel(const float* __restrict__ t1g,
                                                    const float* __restrict__ W2,
                                                    const float* __restrict__ W3,
                                                    const int* __restrict__ bat,
                                                    float* __restrict__ out) {
    __shared__ float W2t[NCH * 32 * 68];  // [c][o2][swz k] padded
    __shared__ float t1l[32 * 260];       // [node][256] padded
    __shared__ float w3l[NCH * 32];
    const int tid = threadIdx.x;
    const int n0 = blockIdx.x * 32;
    const int np = tid >> 3;   // node 0..31
    const int o8 = tid & 7;    // output quad 0..7

    for (int i = tid; i < NCH * 2048; i += 256) {
        int cc = i >> 11, rem = i & 2047;
        int k = rem >> 5, o2 = rem & 31;
        W2t[cc * (32 * 68) + o2 * 68 + ((((k >> 2) ^ (o2 >> 2)) & 15) << 2 | (k & 3))] = W2[i];
    }
    for (int i = tid; i < 32 * 256; i += 256) {
        int nl = i >> 8, j = i & 255;
        t1l[nl * 260 + j] = t1g[(size_t)(n0 + nl) * 256 + j];
    }
    if (tid < NCH * 32) w3l[tid] = W3[tid];
    __syncthreads();

    float y = 0.f;
#pragma unroll
    for (int c = 0; c < NCH; ++c) {
        const float* ip = t1l + np * 260 + c * 64;
        const float* wp = W2t + c * (32 * 68) + (o8 * 4) * 68;
        float a0 = 0.f, a1 = 0.f, a2 = 0.f, a3 = 0.f;
#pragma unroll 4
        for (int kq = 0; kq < 16; ++kq) {
            int skq = ((kq ^ o8) & 15) << 2;
            float4 v = *(const float4*)(ip + (kq << 2));  // 8-lane broadcast
            float4 w0 = *(const float4*)(wp + skq);
            float4 w1 = *(const float4*)(wp + 68 + skq);
            float4 w2 = *(const float4*)(wp + 136 + skq);
            float4 w3 = *(const float4*)(wp + 204 + skq);
            a0 = fmaf(v.x, w0.x, fmaf(v.y, w0.y, fmaf(v.z, w0.z, fmaf(v.w, w0.w, a0))));
            a1 = fmaf(v.x, w1.x, fmaf(v.y, w1.y, fmaf(v.z, w1.z, fmaf(v.w, w1.w, a1))));
            a2 = fmaf(v.x, w2.x, fmaf(v.y, w2.y, fmaf(v.z, w2.z, fmaf(v.w, w2.w, a2))));
            a3 = fmaf(v.x, w3.x, fmaf(v.y, w3.y, fmaf(v.z, w3.z, fmaf(v.w, w3.w, a3))));
        }
        float4 w34 = *(const float4*)(w3l + c * 32 + o8 * 4);
        y += silu_f(a0) * w34.x + silu_f(a1) * w34.y + silu_f(a2) * w34.z + silu_f(a3) * w34.w;
    }
#pragma unroll
    for (int off = 1; off < 8; off <<= 1) y += __shfl_xor(y, off);

    int l = tid & 63;
    int w = tid >> 6;
    float yn = __shfl(y, (l & 7) * 8);
    bool active = l < 8;
    int node = n0 + w * 8 + (l & 7);
    float val = yn * 0.025f;  // /sqrt(4)/20
    int b = bat[node];
    unsigned long long rem = __ballot(active);
    while (rem) {
        int lead = (int)__ffsll(rem) - 1;
        int bl = __shfl(b, lead);
        bool mine = active && (b == bl);
        float t = mine ? val : 0.f;
#pragma unroll
        for (int off = 1; off < 8; off <<= 1) t += __shfl_xor(t, off);
        if (l == lead) atomicAdd(out + bl, t);
        rem &= ~__ballot(mine);
    }
}

extern "C" void kernel_launch(void* const* d_in, const int* in_sizes, int n_in,
                              void* d_out, int out_size, void* d_ws, size_t ws_size,
                              hipStream_t stream) {
    const float* x     = (const float*)d_in[0];
    const int*   ei    = (const int*)d_in[1];
    const int*   bat   = (const int*)d_in[2];
    const float* gamma = (const float*)d_in[3];
    const float* beta  = (const float*)d_in[4];
    const float* Wc1   = (const float*)d_in[5];
    const float* as1   = (const float*)d_in[6];
    const float* ad1   = (const float*)d_in[7];
    const float* Wc2   = (const float*)d_in[8];
    const float* as2   = (const float*)d_in[9];
    const float* ad2   = (const float*)d_in[10];
    const float* Wn1   = (const float*)d_in[11];
    const float* Wn2   = (const float*)d_in[12];
    const float* Wout  = (const float*)d_in[13];
    float* out = (float*)d_out;

    // workspace layout (floats)
    float* A    = (float*)d_ws;            // C1h/C2h fp16 conv outs
    float* B    = A + 10240000;            // Bh fp16 proj h / t1g f32
    float* es   = B + 5120000;             // 80k
    float* ed   = es + 80000;              // 80k
    int* rowp   = (int*)(ed + 80000);      // 20001 (pad 20004)
    int* cnt    = rowp + 20004;            // 20000
    int* fillc  = cnt + 20000;             // 20000
    int* csr    = fillc + 20000;           // 400000
    int* bsum   = csr + 400000;            // 128
    int* boff   = bsum + 128;              // 128
    __half* C1h = (__half*)A;              // conv1 out (silu'd, fp16) [N,256]
    __half* C2h = (__half*)(A + 2560000);  // conv2 out (silu'd, fp16) [N,256]
    __half* Bh  = (__half*)B;              // proj h (fp16) for gathers
    float* t1g  = B;                       // mlp hidden f32 (Bh dead after gather2)

    dim3 blk(256);
    const int NB = (N_ATOMS + 255) / 256;   // 79
    const int NT64 = (N_ATOMS + 63) / 64;   // 313 (64-node proj blocks)
    const int NT = N_ATOMS / 32;            // 625 (mlp23)

    // ---- CSR build (graph is shared by both convs) ----
    fill_kernel<<<80, blk, 0, stream>>>((float*)cnt, 40000, 0.f);  // cnt + fillc (adjacent)
    hist_kernel<<<(N_EDGES + 255) / 256, blk, 0, stream>>>(ei, cnt, N_EDGES);
    scan_l1_kernel<<<NB, blk, 0, stream>>>(cnt, rowp, bsum, N_ATOMS);
    scan_l2_kernel<<<1, blk, 0, stream>>>(bsum, boff, rowp + N_ATOMS, NB, out);
    scan_l3_kernel<<<NB, blk, 0, stream>>>(rowp, boff, N_ATOMS);
    scatter_kernel<<<(N_EDGES + 255) / 256, blk, 0, stream>>>(ei, rowp, fillc, csr, N_EDGES);

    // ---- conv1 (LN fused into proj staging; h fp16) ----
    proj_kernel<128, NCH * F_IN, false, true, true, false, true>
        <<<dim3(NT64, NCH), blk, 0, stream>>>(x, gamma, beta, Wc1, as1, ad1, Bh, es, ed);
    gat_gather_kernel<<<N_ATOMS / 4, blk, 0, stream>>>(rowp, csr, es, ed, Bh, C1h);

    // ---- conv2 (fp16 input staging) ----
    proj_kernel<64, 256, true, false, true, false, true>
        <<<dim3(NT64, NCH), blk, 0, stream>>>(C1h, gamma, beta, Wc2, as2, ad2, Bh, es, ed);
    gat_gather_kernel<<<N_ATOMS / 4, blk, 0, stream>>>(rowp, csr, es, ed, Bh, C2h);

    // ---- MLP: layer1 via proj structure (fp16 in, silu out, f32), then 64->32->1 ----
    proj_kernel<64, 256, true, false, false, true, false>
        <<<dim3(NT64, NCH), blk, 0, stream>>>(C2h, gamma, beta, Wn1, as1, ad1, t1g, es, ed);
    mlp23_kernel<<<NT, blk, 0, stream>>>(t1g, Wn2, Wout, bat, out);
}

// Round 18
// 210.492 us; speedup vs baseline: 1.0944x; 1.0944x over previous
//
#include <hip/hip_runtime.h>
#include <hip/hip_bf16.h>
#include <hip/hip_fp16.h>

// Problem constants (match reference)
#define N_ATOMS 20000
#define N_EDGES 400000
#define NCH 4
#define F_IN 128
#define S_OUT 32

// ---------- helpers ----------
__device__ __forceinline__ float silu_f(float v) { return v / (1.f + __expf(-v)); }

typedef _Float16 half8v __attribute__((ext_vector_type(8)));
typedef float f32x4v __attribute__((ext_vector_type(4)));

__device__ __forceinline__ half8v ld_frag(const __half* p) {
    union { float4 f; half8v h; } u;
    u.f = *(const float4*)p;
    return u.h;
}

__device__ __forceinline__ int wave_iscan(int v, int l) {
#pragma unroll
    for (int off = 1; off < 64; off <<= 1) {
        int t = __shfl_up(v, off);
        if (l >= off) v += t;
    }
    return v;
}

// ---------- fill ----------
__global__ void fill_kernel(float* __restrict__ p, int n, float v) {
    int i = blockIdx.x * blockDim.x + threadIdx.x;
    int stride = gridDim.x * blockDim.x;
    for (; i < n; i += stride) p[i] = v;
}

// ---------- CSR build: histogram -> hierarchical scan -> scatter ----------
__global__ void hist_kernel(const int* __restrict__ ei, int* __restrict__ cnt, int E) {
    int e = blockIdx.x * 256 + threadIdx.x;
    if (e < E) atomicAdd(&cnt[ei[E + e]], 1);
}

__global__ __launch_bounds__(256) void scan_l1_kernel(const int* __restrict__ cnt,
                                                      int* __restrict__ rowp,
                                                      int* __restrict__ bsum, int n) {
    int i = blockIdx.x * 256 + threadIdx.x;
    int l = threadIdx.x & 63, w = threadIdx.x >> 6;
    int v = (i < n) ? cnt[i] : 0;
    int incl = wave_iscan(v, l);
    __shared__ int wsum[4];
    if (l == 63) wsum[w] = incl;
    __syncthreads();
    int add = 0;
#pragma unroll
    for (int j = 0; j < 4; ++j) add += (j < w) ? wsum[j] : 0;
    if (i < n) rowp[i] = add + incl - v;
    if (threadIdx.x == 255) bsum[blockIdx.x] = add + incl;
}

__global__ __launch_bounds__(256) void scan_l2_kernel(const int* __restrict__ bsum,
                                                      int* __restrict__ boff,
                                                      int* __restrict__ rowp_n, int nb,
                                                      float* __restrict__ out_zero) {
    int i = threadIdx.x;
    if (i < S_OUT) out_zero[i] = 0.f;  // fused energies zero-init
    int l = i & 63, w = i >> 6;
    int v = (i < nb) ? bsum[i] : 0;
    int incl = wave_iscan(v, l);
    __shared__ int wsum[4];
    if (l == 63) wsum[w] = incl;
    __syncthreads();
    int add = 0;
#pragma unroll
    for (int j = 0; j < 4; ++j) add += (j < w) ? wsum[j] : 0;
    if (i < nb) boff[i] = add + incl - v;
    if (i == nb - 1) *rowp_n = add + incl;
}

__global__ __launch_bounds__(256) void scan_l3_kernel(int* __restrict__ rowp,
                                                      const int* __restrict__ boff, int n) {
    int i = blockIdx.x * 256 + threadIdx.x;
    if (i < n) rowp[i] += boff[blockIdx.x];
}

__global__ void scatter_kernel(const int* __restrict__ ei, const int* __restrict__ rowp,
                               int* __restrict__ fill, int* __restrict__ csr_src, int E) {
    int e = blockIdx.x * 256 + threadIdx.x;
    if (e < E) {
        int d = ei[E + e];
        int pos = rowp[d] + atomicAdd(&fill[d], 1);
        csr_src[pos] = ei[e];
    }
}

// ---------- projection via MFMA: block = 64 nodes x 64 outputs, c = blockIdx.y ----------
// 4 waves; wave w owns C rows 16w..16w+15 (A-frag lane&15 = row). Wt transposed [o][k]
// with octet store-swizzle (read XORs back). Per K=32 step: 1 A + 4 B b128 reads + 4 mfma.
// K-permutation applied identically to A and B frags cancels in the dot product.
template <int FIN, int IN_STRIDE, bool IN_HALF, bool LN, bool ATT, bool SILU_OUT, bool OUT_HALF>
__global__ __launch_bounds__(256) void proj_kernel(const void* __restrict__ inv,
                                                   const float* __restrict__ gamma,
                                                   const float* __restrict__ beta,
                                                   const float* __restrict__ W,
                                                   const float* __restrict__ a_src,
                                                   const float* __restrict__ a_dst,
                                                   void* __restrict__ outv,
                                                   float* __restrict__ es,
                                                   float* __restrict__ ed) {
    constexpr int OCT = FIN / 8;      // octets per row
    constexpr int OM = OCT - 1;
    constexpr int WSH = FIN + 8;      // halves stride (rows 16B-aligned: (FIN+8)*2 % 16 == 0)
    __shared__ __half Wt[64 * WSH];   // [o][store-swizzled k]
    __shared__ __half inl[64 * WSH];  // [node][k] linear
    const int tid = threadIdx.x;
    const int c = blockIdx.y;
    const int n0 = blockIdx.x * 64;
    const int w = tid >> 6;           // wave 0..3
    const int l = tid & 63;
    const int col = l & 15;           // MFMA row/col lane index
    const int g = l >> 4;             // k-octet group 0..3

    // stage W transposed (pack k-pairs to half2; octet store-swizzle by o>>2)
    const float* __restrict__ Wc = W + c * (FIN * 64);
    for (int i = tid; i < (FIN / 2) * 64; i += 256) {
        int kp = i >> 6, oo = i & 63;
        int k = kp * 2;
        float w0 = Wc[(size_t)k * 64 + oo];
        float w1 = Wc[(size_t)(k + 1) * 64 + oo];
        int pos = ((((k >> 3) ^ (oo >> 2)) & OM) << 3) | (k & 7);
        *(__half2*)(&Wt[oo * WSH + pos]) = __floats2half2_rn(w0, w1);
    }
    // stage 64 input rows, vectorized by 8-element chunks (clamped; stores guarded later)
    if (IN_HALF) {
        const __half* __restrict__ inh = (const __half*)inv;
        for (int i = tid; i < 64 * (FIN / 8); i += 256) {
            int nl = i / (FIN / 8), ch = i % (FIN / 8);
            int node = min(n0 + nl, N_ATOMS - 1);
            *(float4*)(inl + nl * WSH + ch * 8) =
                *(const float4*)(inh + (size_t)node * IN_STRIDE + c * FIN + ch * 8);
        }
    } else {
        const float* __restrict__ inf = (const float*)inv;
        for (int i = tid; i < 64 * (FIN / 8); i += 256) {
            int nl = i / (FIN / 8), ch = i % (FIN / 8);
            int node = min(n0 + nl, N_ATOMS - 1);
            const float* src = inf + (size_t)node * IN_STRIDE + c * FIN + ch * 8;
            float4 a = *(const float4*)src;
            float4 b = *(const float4*)(src + 4);
            float4 st;
            __half2* sp = (__half2*)&st;
            sp[0] = __floats2half2_rn(a.x, a.y);
            sp[1] = __floats2half2_rn(a.z, a.w);
            sp[2] = __floats2half2_rn(b.x, b.y);
            sp[3] = __floats2half2_rn(b.z, b.w);
            *(float4*)(inl + nl * WSH + ch * 8) = st;
        }
    }
    __syncthreads();

    if (LN) {  // in-place LayerNorm per 128-row; wave w owns rows 16w..16w+15
        float gl0 = gamma[l], gl1 = gamma[l + 64];
        float bl0 = beta[l], bl1 = beta[l + 64];
#pragma unroll
        for (int r = 0; r < 16; ++r) {
            int row = w * 16 + r;
            float v0 = __half2float(inl[row * WSH + l]);
            float v1 = __half2float(inl[row * WSH + l + 64]);
            float s = v0 + v1, sq = v0 * v0 + v1 * v1;
#pragma unroll
            for (int off = 32; off; off >>= 1) {
                s += __shfl_xor(s, off);
                sq += __shfl_xor(sq, off);
            }
            float mu = s * (1.f / 128.f);
            float rs = rsqrtf(sq * (1.f / 128.f) - mu * mu + 1e-5f);
            inl[row * WSH + l]      = __float2half((v0 - mu) * rs * gl0 + bl0);
            inl[row * WSH + l + 64] = __float2half((v1 - mu) * rs * gl1 + bl1);
        }
        __syncthreads();
    }

    // MFMA K-loop
    f32x4v acc[4];
#pragma unroll
    for (int t = 0; t < 4; ++t) acc[t] = (f32x4v){0.f, 0.f, 0.f, 0.f};

    const __half* arow = inl + (w * 16 + col) * WSH + g * 8;
#pragma unroll
    for (int it = 0; it < FIN / 32; ++it) {
        half8v af = ld_frag(arow + it * 32);
        int J = it * 4 + g;
#pragma unroll
        for (int t = 0; t < 4; ++t) {
            int oo = 16 * t + col;
            half8v bf = ld_frag(Wt + oo * WSH + (((J ^ (oo >> 2)) & OM) << 3));
            acc[t] = __builtin_amdgcn_mfma_f32_16x16x32_f16(af, bf, acc[t], 0, 0, 0);
        }
    }

    // epilogue: D layout col=lane&15, row=(lane>>4)*4+reg  [verified m89]
    float av[4], bv[4];
    if (ATT) {
#pragma unroll
        for (int t = 0; t < 4; ++t) {
            av[t] = a_src[c * 64 + 16 * t + col];
            bv[t] = a_dst[c * 64 + 16 * t + col];
        }
    }
#pragma unroll
    for (int r = 0; r < 4; ++r) {
        int node = n0 + w * 16 + g * 4 + r;
        bool valid = node < N_ATOMS;
        if (valid) {
#pragma unroll
            for (int t = 0; t < 4; ++t) {
                float o = acc[t][r];
                if (SILU_OUT) o = silu_f(o);
                if (OUT_HALF)
                    ((__half*)outv)[(size_t)node * 256 + c * 64 + 16 * t + col] = __float2half(o);
                else
                    ((float*)outv)[(size_t)node * 256 + c * 64 + 16 * t + col] = o;
            }
        }
        if (ATT) {
            float ps = 0.f, pd = 0.f;
#pragma unroll
            for (int t = 0; t < 4; ++t) {
                ps = fmaf(acc[t][r], av[t], ps);
                pd = fmaf(acc[t][r], bv[t], pd);
            }
#pragma unroll
            for (int off = 1; off < 16; off <<= 1) {
                ps += __shfl_xor(ps, off);
                pd += __shfl_xor(pd, off);
            }
            if (col == 0 && valid) { es[node * NCH + c] = ps; ed[node * NCH + c] = pd; }
        }
    }
}

// ---------- fused GAT aggregation: ONE wave per dst, all 4 channels ----------
__global__ __launch_bounds__(256) void gat_gather_kernel(const int* __restrict__ rowp,
                                                         const int* __restrict__ csr_src,
                                                         const float* __restrict__ es,
                                                         const float* __restrict__ ed,
                                                         const __half* __restrict__ h,
                                                         __half* __restrict__ out) {
    int l = threadIdx.x & 63;
    int d = blockIdx.x * 4 + (threadIdx.x >> 6);
    int c = l >> 4, q = l & 15;
    int r0 = rowp[d], r1 = rowp[d + 1];
    float edc = ed[d * NCH + c];
    float m = -1e30f, den = 0.f;
    float a0 = 0.f, a1 = 0.f, a2 = 0.f, a3 = 0.f;
    int grp = l & 48;

    for (int base = r0; base < r1; base += 16) {
        int len = min(16, r1 - base);
        float logit = -1e30f;
        int s = 0;
        if (q < len) {
            s = csr_src[base + q];
            float v = es[s * NCH + c] + edc;
            logit = v >= 0.f ? v : 0.2f * v;
        }
        float cm = logit;
#pragma unroll
        for (int off = 8; off; off >>= 1) cm = fmaxf(cm, __shfl_xor(cm, off));
        float nm = fmaxf(m, cm);
        float resc = __expf(m - nm);
        float ex = (q < len) ? __expf(logit - nm) : 0.f;
        float cs = ex;
#pragma unroll
        for (int off = 8; off; off >>= 1) cs += __shfl_xor(cs, off);
        den = den * resc + cs;
        a0 *= resc; a1 *= resc; a2 *= resc; a3 *= resc;
        m = nm;
        int e = 0;
        for (; e + 2 <= len; e += 2) {
            int s0 = __shfl(s, e);
            int s1 = __shfl(s, e + 1);
            float x0 = __shfl(ex, grp | e);
            float x1 = __shfl(ex, grp | (e + 1));
            float2 hv0 = *(const float2*)(h + (size_t)s0 * 256 + l * 4);
            float2 hv1 = *(const float2*)(h + (size_t)s1 * 256 + l * 4);
            __half2* hp0 = (__half2*)&hv0;
            __half2* hp1 = (__half2*)&hv1;
            float2 f00 = __half22float2(hp0[0]), f01 = __half22float2(hp0[1]);
            float2 f10 = __half22float2(hp1[0]), f11 = __half22float2(hp1[1]);
            a0 = fmaf(x0, f00.x, fmaf(x1, f10.x, a0));
            a1 = fmaf(x0, f00.y, fmaf(x1, f10.y, a1));
            a2 = fmaf(x0, f01.x, fmaf(x1, f11.x, a2));
            a3 = fmaf(x0, f01.y, fmaf(x1, f11.y, a3));
        }
        for (; e < len; ++e) {
            int se = __shfl(s, e);
            float xe = __shfl(ex, grp | e);
            float2 hv = *(const float2*)(h + (size_t)se * 256 + l * 4);
            __half2* hp = (__half2*)&hv;
            float2 f0 = __half22float2(hp[0]), f1 = __half22float2(hp[1]);
            a0 = fmaf(xe, f0.x, a0);
            a1 = fmaf(xe, f0.y, a1);
            a2 = fmaf(xe, f1.x, a2);
            a3 = fmaf(xe, f1.y, a3);
        }
    }
    float inv = 1.f / (den + 1e-16f);
    float2 st;
    __half2* sp = (__half2*)&st;
    sp[0] = __floats2half2_rn(silu_f(a0 * inv), silu_f(a1 * inv));
    sp[1] = __floats2half2_rn(silu_f(a2 * inv), silu_f(a3 * inv));
    *(float2*)(out + (size_t)d * 256 + l * 4) = st;
}

// ---------- MLP layers 2+3 (64->32->1, all channels) + energy reduction ----------
__global__ __launch_bounds__(256) void mlp23_kernel(const float* __restrict__ t1g,
                                                    const float* __restrict__ W2,
                                                    const float* __restrict__ W3,
                                                    const int* __restrict__ bat,
                                                    float* __restrict__ out) {
    __shared__ float W2t[NCH * 32 * 68];  // [c][o2][swz k] padded
    __shared__ float t1l[32 * 260];       // [node][256] padded
    __shared__ float w3l[NCH * 32];
    const int tid = threadIdx.x;
    const int n0 = blockIdx.x * 32;
    const int np = tid >> 3;   // node 0..31
    const int o8 = tid & 7;    // output quad 0..7

    for (int i = tid; i < NCH * 2048; i += 256) {
        int cc = i >> 11, rem = i & 2047;
        int k = rem >> 5, o2 = rem & 31;
        W2t[cc * (32 * 68) + o2 * 68 + ((((k >> 2) ^ (o2 >> 2)) & 15) << 2 | (k & 3))] = W2[i];
    }
    for (int i = tid; i < 32 * 256; i += 256) {
        int nl = i >> 8, j = i & 255;
        t1l[nl * 260 + j] = t1g[(size_t)(n0 + nl) * 256 + j];
    }
    if (tid < NCH * 32) w3l[tid] = W3[tid];
    __syncthreads();

    float y = 0.f;
#pragma unroll
    for (int c = 0; c < NCH; ++c) {
        const float* ip = t1l + np * 260 + c * 64;
        const float* wp = W2t + c * (32 * 68) + (o8 * 4) * 68;
        float a0 = 0.f, a1 = 0.f, a2 = 0.f, a3 = 0.f;
#pragma unroll 4
        for (int kq = 0; kq < 16; ++kq) {
            int skq = ((kq ^ o8) & 15) << 2;
            float4 v = *(const float4*)(ip + (kq << 2));  // 8-lane broadcast
            float4 w0 = *(const float4*)(wp + skq);
            float4 w1 = *(const float4*)(wp + 68 + skq);
            float4 w2 = *(const float4*)(wp + 136 + skq);
            float4 w3 = *(const float4*)(wp + 204 + skq);
            a0 = fmaf(v.x, w0.x, fmaf(v.y, w0.y, fmaf(v.z, w0.z, fmaf(v.w, w0.w, a0))));
            a1 = fmaf(v.x, w1.x, fmaf(v.y, w1.y, fmaf(v.z, w1.z, fmaf(v.w, w1.w, a1))));
            a2 = fmaf(v.x, w2.x, fmaf(v.y, w2.y, fmaf(v.z, w2.z, fmaf(v.w, w2.w, a2))));
            a3 = fmaf(v.x, w3.x, fmaf(v.y, w3.y, fmaf(v.z, w3.z, fmaf(v.w, w3.w, a3))));
        }
        float4 w34 = *(const float4*)(w3l + c * 32 + o8 * 4);
        y += silu_f(a0) * w34.x + silu_f(a1) * w34.y + silu_f(a2) * w34.z + silu_f(a3) * w34.w;
    }
#pragma unroll
    for (int off = 1; off < 8; off <<= 1) y += __shfl_xor(y, off);

    int l = tid & 63;
    int w = tid >> 6;
    float yn = __shfl(y, (l & 7) * 8);
    bool active = l < 8;
    int node = n0 + w * 8 + (l & 7);
    float val = yn * 0.025f;  // /sqrt(4)/20
    int b = bat[node];
    unsigned long long rem = __ballot(active);
    while (rem) {
        int lead = (int)__ffsll(rem) - 1;
        int bl = __shfl(b, lead);
        bool mine = active && (b == bl);
        float t = mine ? val : 0.f;
#pragma unroll
        for (int off = 1; off < 8; off <<= 1) t += __shfl_xor(t, off);
        if (l == lead) atomicAdd(out + bl, t);
        rem &= ~__ballot(mine);
    }
}

extern "C" void kernel_launch(void* const* d_in, const int* in_sizes, int n_in,
                              void* d_out, int out_size, void* d_ws, size_t ws_size,
                              hipStream_t stream) {
    const float* x     = (const float*)d_in[0];
    const int*   ei    = (const int*)d_in[1];
    const int*   bat   = (const int*)d_in[2];
    const float* gamma = (const float*)d_in[3];
    const float* beta  = (const float*)d_in[4];
    const float* Wc1   = (const float*)d_in[5];
    const float* as1   = (const float*)d_in[6];
    const float* ad1   = (const float*)d_in[7];
    const float* Wc2   = (const float*)d_in[8];
    const float* as2   = (const float*)d_in[9];
    const float* ad2   = (const float*)d_in[10];
    const float* Wn1   = (const float*)d_in[11];
    const float* Wn2   = (const float*)d_in[12];
    const float* Wout  = (const float*)d_in[13];
    float* out = (float*)d_out;

    // workspace layout (floats)
    float* A    = (float*)d_ws;            // C1h/C2h fp16 conv outs
    float* B    = A + 10240000;            // Bh fp16 proj h / t1g f32
    float* es   = B + 5120000;             // 80k
    float* ed   = es + 80000;              // 80k
    int* rowp   = (int*)(ed + 80000);      // 20001 (pad 20004)
    int* cnt    = rowp + 20004;            // 20000
    int* fillc  = cnt + 20000;             // 20000
    int* csr    = fillc + 20000;           // 400000
    int* bsum   = csr + 400000;            // 128
    int* boff   = bsum + 128;              // 128
    __half* C1h = (__half*)A;              // conv1 out (silu'd, fp16) [N,256]
    __half* C2h = (__half*)(A + 2560000);  // conv2 out (silu'd, fp16) [N,256]
    __half* Bh  = (__half*)B;              // proj h (fp16) for gathers
    float* t1g  = B;                       // mlp hidden f32 (Bh dead after gather2)

    dim3 blk(256);
    const int NB = (N_ATOMS + 255) / 256;   // 79
    const int NT64 = (N_ATOMS + 63) / 64;   // 313 (64-node proj blocks)
    const int NT = N_ATOMS / 32;            // 625 (mlp23)

    // ---- CSR build (graph is shared by both convs) ----
    fill_kernel<<<80, blk, 0, stream>>>((float*)cnt, 40000, 0.f);  // cnt + fillc (adjacent)
    hist_kernel<<<(N_EDGES + 255) / 256, blk, 0, stream>>>(ei, cnt, N_EDGES);
    scan_l1_kernel<<<NB, blk, 0, stream>>>(cnt, rowp, bsum, N_ATOMS);
    scan_l2_kernel<<<1, blk, 0, stream>>>(bsum, boff, rowp + N_ATOMS, NB, out);
    scan_l3_kernel<<<NB, blk, 0, stream>>>(rowp, boff, N_ATOMS);
    scatter_kernel<<<(N_EDGES + 255) / 256, blk, 0, stream>>>(ei, rowp, fillc, csr, N_EDGES);

    // ---- conv1 (LN fused into proj staging; h fp16) ----
    proj_kernel<128, NCH * F_IN, false, true, true, false, true>
        <<<dim3(NT64, NCH), blk, 0, stream>>>(x, gamma, beta, Wc1, as1, ad1, Bh, es, ed);
    gat_gather_kernel<<<N_ATOMS / 4, blk, 0, stream>>>(rowp, csr, es, ed, Bh, C1h);

    // ---- conv2 (fp16 input staging) ----
    proj_kernel<64, 256, true, false, true, false, true>
        <<<dim3(NT64, NCH), blk, 0, stream>>>(C1h, gamma, beta, Wc2, as2, ad2, Bh, es, ed);
    gat_gather_kernel<<<N_ATOMS / 4, blk, 0, stream>>>(rowp, csr, es, ed, Bh, C2h);

    // ---- MLP: layer1 via MFMA proj (fp16 in, silu out, f32), then 64->32->1 ----
    proj_kernel<64, 256, true, false, false, true, false>
        <<<dim3(NT64, NCH), blk, 0, stream>>>(C2h, gamma, beta, Wn1, as1, ad1, t1g, es, ed);
    mlp23_kernel<<<NT, blk, 0, stream>>>(t1g, Wn2, Wout, bat, out);
}

// Round 19
// 186.239 us; speedup vs baseline: 1.2370x; 1.1302x over previous
//
#include <hip/hip_runtime.h>
#include <hip/hip_bf16.h>
#include <hip/hip_fp16.h>

// Problem constants (match reference)
#define N_ATOMS 20000
#define N_EDGES 400000
#define NCH 4
#define F_IN 128
#define S_OUT 32

// ---------- helpers ----------
__device__ __forceinline__ float silu_f(float v) { return v / (1.f + __expf(-v)); }

typedef _Float16 half8v __attribute__((ext_vector_type(8)));
typedef float f32x4v __attribute__((ext_vector_type(4)));

__device__ __forceinline__ half8v ld_frag(const __half* p) {
    union { float4 f; half8v h; } u;
    u.f = *(const float4*)p;
    return u.h;
}

__device__ __forceinline__ int wave_iscan(int v, int l) {
#pragma unroll
    for (int off = 1; off < 64; off <<= 1) {
        int t = __shfl_up(v, off);
        if (l >= off) v += t;
    }
    return v;
}

// ---------- fill ----------
__global__ void fill_kernel(float* __restrict__ p, int n, float v) {
    int i = blockIdx.x * blockDim.x + threadIdx.x;
    int stride = gridDim.x * blockDim.x;
    for (; i < n; i += stride) p[i] = v;
}

// ---------- CSR build: histogram -> hierarchical scan -> scatter ----------
__global__ void hist_kernel(const int* __restrict__ ei, int* __restrict__ cnt, int E) {
    int e = blockIdx.x * 256 + threadIdx.x;
    if (e < E) atomicAdd(&cnt[ei[E + e]], 1);
}

__global__ __launch_bounds__(256) void scan_l1_kernel(const int* __restrict__ cnt,
                                                      int* __restrict__ rowp,
                                                      int* __restrict__ bsum, int n) {
    int i = blockIdx.x * 256 + threadIdx.x;
    int l = threadIdx.x & 63, w = threadIdx.x >> 6;
    int v = (i < n) ? cnt[i] : 0;
    int incl = wave_iscan(v, l);
    __shared__ int wsum[4];
    if (l == 63) wsum[w] = incl;
    __syncthreads();
    int add = 0;
#pragma unroll
    for (int j = 0; j < 4; ++j) add += (j < w) ? wsum[j] : 0;
    if (i < n) rowp[i] = add + incl - v;
    if (threadIdx.x == 255) bsum[blockIdx.x] = add + incl;
}

__global__ __launch_bounds__(256) void scan_l2_kernel(const int* __restrict__ bsum,
                                                      int* __restrict__ boff,
                                                      int* __restrict__ rowp_n, int nb,
                                                      float* __restrict__ out_zero) {
    int i = threadIdx.x;
    if (i < S_OUT) out_zero[i] = 0.f;  // fused energies zero-init
    int l = i & 63, w = i >> 6;
    int v = (i < nb) ? bsum[i] : 0;
    int incl = wave_iscan(v, l);
    __shared__ int wsum[4];
    if (l == 63) wsum[w] = incl;
    __syncthreads();
    int add = 0;
#pragma unroll
    for (int j = 0; j < 4; ++j) add += (j < w) ? wsum[j] : 0;
    if (i < nb) boff[i] = add + incl - v;
    if (i == nb - 1) *rowp_n = add + incl;
}

__global__ __launch_bounds__(256) void scan_l3_kernel(int* __restrict__ rowp,
                                                      const int* __restrict__ boff, int n) {
    int i = blockIdx.x * 256 + threadIdx.x;
    if (i < n) rowp[i] += boff[blockIdx.x];
}

__global__ void scatter_kernel(const int* __restrict__ ei, const int* __restrict__ rowp,
                               int* __restrict__ fill, int* __restrict__ csr_src, int E) {
    int e = blockIdx.x * 256 + threadIdx.x;
    if (e < E) {
        int d = ei[E + e];
        int pos = rowp[d] + atomicAdd(&fill[d], 1);
        csr_src[pos] = ei[e];
    }
}

// ---------- projection via MFMA: block = 64 nodes x 64 outputs, c = blockIdx.y ----------
template <int FIN, int IN_STRIDE, bool IN_HALF, bool LN, bool ATT, bool SILU_OUT, bool OUT_HALF>
__global__ __launch_bounds__(256) void proj_kernel(const void* __restrict__ inv,
                                                   const float* __restrict__ gamma,
                                                   const float* __restrict__ beta,
                                                   const float* __restrict__ W,
                                                   const float* __restrict__ a_src,
                                                   const float* __restrict__ a_dst,
                                                   void* __restrict__ outv,
                                                   float* __restrict__ es,
                                                   float* __restrict__ ed) {
    constexpr int OCT = FIN / 8;      // octets per row
    constexpr int OM = OCT - 1;
    constexpr int WSH = FIN + 8;      // halves stride (rows 16B-aligned)
    __shared__ __half Wt[64 * WSH];   // [o][store-swizzled k]
    __shared__ __half inl[64 * WSH];  // [node][k] linear
    const int tid = threadIdx.x;
    const int c = blockIdx.y;
    const int n0 = blockIdx.x * 64;
    const int w = tid >> 6;           // wave 0..3
    const int l = tid & 63;
    const int col = l & 15;           // MFMA row/col lane index
    const int g = l >> 4;             // k-octet group 0..3

    const float* __restrict__ Wc = W + c * (FIN * 64);
    for (int i = tid; i < (FIN / 2) * 64; i += 256) {
        int kp = i >> 6, oo = i & 63;
        int k = kp * 2;
        float w0 = Wc[(size_t)k * 64 + oo];
        float w1 = Wc[(size_t)(k + 1) * 64 + oo];
        int pos = ((((k >> 3) ^ (oo >> 2)) & OM) << 3) | (k & 7);
        *(__half2*)(&Wt[oo * WSH + pos]) = __floats2half2_rn(w0, w1);
    }
    if (IN_HALF) {
        const __half* __restrict__ inh = (const __half*)inv;
        for (int i = tid; i < 64 * (FIN / 8); i += 256) {
            int nl = i / (FIN / 8), ch = i % (FIN / 8);
            int node = min(n0 + nl, N_ATOMS - 1);
            *(float4*)(inl + nl * WSH + ch * 8) =
                *(const float4*)(inh + (size_t)node * IN_STRIDE + c * FIN + ch * 8);
        }
    } else {
        const float* __restrict__ inf = (const float*)inv;
        for (int i = tid; i < 64 * (FIN / 8); i += 256) {
            int nl = i / (FIN / 8), ch = i % (FIN / 8);
            int node = min(n0 + nl, N_ATOMS - 1);
            const float* src = inf + (size_t)node * IN_STRIDE + c * FIN + ch * 8;
            float4 a = *(const float4*)src;
            float4 b = *(const float4*)(src + 4);
            float4 st;
            __half2* sp = (__half2*)&st;
            sp[0] = __floats2half2_rn(a.x, a.y);
            sp[1] = __floats2half2_rn(a.z, a.w);
            sp[2] = __floats2half2_rn(b.x, b.y);
            sp[3] = __floats2half2_rn(b.z, b.w);
            *(float4*)(inl + nl * WSH + ch * 8) = st;
        }
    }
    __syncthreads();

    if (LN) {  // in-place LayerNorm per 128-row; wave w owns rows 16w..16w+15
        float gl0 = gamma[l], gl1 = gamma[l + 64];
        float bl0 = beta[l], bl1 = beta[l + 64];
#pragma unroll
        for (int r = 0; r < 16; ++r) {
            int row = w * 16 + r;
            float v0 = __half2float(inl[row * WSH + l]);
            float v1 = __half2float(inl[row * WSH + l + 64]);
            float s = v0 + v1, sq = v0 * v0 + v1 * v1;
#pragma unroll
            for (int off = 32; off; off >>= 1) {
                s += __shfl_xor(s, off);
                sq += __shfl_xor(sq, off);
            }
            float mu = s * (1.f / 128.f);
            float rs = rsqrtf(sq * (1.f / 128.f) - mu * mu + 1e-5f);
            inl[row * WSH + l]      = __float2half((v0 - mu) * rs * gl0 + bl0);
            inl[row * WSH + l + 64] = __float2half((v1 - mu) * rs * gl1 + bl1);
        }
        __syncthreads();
    }

    f32x4v acc[4];
#pragma unroll
    for (int t = 0; t < 4; ++t) acc[t] = (f32x4v){0.f, 0.f, 0.f, 0.f};

    const __half* arow = inl + (w * 16 + col) * WSH + g * 8;
#pragma unroll
    for (int it = 0; it < FIN / 32; ++it) {
        half8v af = ld_frag(arow + it * 32);
        int J = it * 4 + g;
#pragma unroll
        for (int t = 0; t < 4; ++t) {
            int oo = 16 * t + col;
            half8v bf = ld_frag(Wt + oo * WSH + (((J ^ (oo >> 2)) & OM) << 3));
            acc[t] = __builtin_amdgcn_mfma_f32_16x16x32_f16(af, bf, acc[t], 0, 0, 0);
        }
    }

    // epilogue: D layout col=lane&15, row=(lane>>4)*4+reg
    float av[4], bv[4];
    if (ATT) {
#pragma unroll
        for (int t = 0; t < 4; ++t) {
            av[t] = a_src[c * 64 + 16 * t + col];
            bv[t] = a_dst[c * 64 + 16 * t + col];
        }
    }
#pragma unroll
    for (int r = 0; r < 4; ++r) {
        int node = n0 + w * 16 + g * 4 + r;
        bool valid = node < N_ATOMS;
        if (valid) {
#pragma unroll
            for (int t = 0; t < 4; ++t) {
                float o = acc[t][r];
                if (SILU_OUT) o = silu_f(o);
                if (OUT_HALF)
                    ((__half*)outv)[(size_t)node * 256 + c * 64 + 16 * t + col] = __float2half(o);
                else
                    ((float*)outv)[(size_t)node * 256 + c * 64 + 16 * t + col] = o;
            }
        }
        if (ATT) {
            float ps = 0.f, pd = 0.f;
#pragma unroll
            for (int t = 0; t < 4; ++t) {
                ps = fmaf(acc[t][r], av[t], ps);
                pd = fmaf(acc[t][r], bv[t], pd);
            }
#pragma unroll
            for (int off = 1; off < 16; off <<= 1) {
                ps += __shfl_xor(ps, off);
                pd += __shfl_xor(pd, off);
            }
            if (col == 0 && valid) { es[node * NCH + c] = ps; ed[node * NCH + c] = pd; }
        }
    }
}

// ---------- fused GAT aggregation: ONE wave per dst, all 4 channels ----------
__global__ __launch_bounds__(256) void gat_gather_kernel(const int* __restrict__ rowp,
                                                         const int* __restrict__ csr_src,
                                                         const float* __restrict__ es,
                                                         const float* __restrict__ ed,
                                                         const __half* __restrict__ h,
                                                         __half* __restrict__ out) {
    int l = threadIdx.x & 63;
    int d = blockIdx.x * 4 + (threadIdx.x >> 6);
    int c = l >> 4, q = l & 15;
    int r0 = rowp[d], r1 = rowp[d + 1];
    float edc = ed[d * NCH + c];
    float m = -1e30f, den = 0.f;
    float a0 = 0.f, a1 = 0.f, a2 = 0.f, a3 = 0.f;
    int grp = l & 48;

    for (int base = r0; base < r1; base += 16) {
        int len = min(16, r1 - base);
        float logit = -1e30f;
        int s = 0;
        if (q < len) {
            s = csr_src[base + q];
            float v = es[s * NCH + c] + edc;
            logit = v >= 0.f ? v : 0.2f * v;
        }
        float cm = logit;
#pragma unroll
        for (int off = 8; off; off >>= 1) cm = fmaxf(cm, __shfl_xor(cm, off));
        float nm = fmaxf(m, cm);
        float resc = __expf(m - nm);
        float ex = (q < len) ? __expf(logit - nm) : 0.f;
        float cs = ex;
#pragma unroll
        for (int off = 8; off; off >>= 1) cs += __shfl_xor(cs, off);
        den = den * resc + cs;
        a0 *= resc; a1 *= resc; a2 *= resc; a3 *= resc;
        m = nm;
        int e = 0;
        for (; e + 2 <= len; e += 2) {
            int s0 = __shfl(s, e);
            int s1 = __shfl(s, e + 1);
            float x0 = __shfl(ex, grp | e);
            float x1 = __shfl(ex, grp | (e + 1));
            float2 hv0 = *(const float2*)(h + (size_t)s0 * 256 + l * 4);
            float2 hv1 = *(const float2*)(h + (size_t)s1 * 256 + l * 4);
            __half2* hp0 = (__half2*)&hv0;
            __half2* hp1 = (__half2*)&hv1;
            float2 f00 = __half22float2(hp0[0]), f01 = __half22float2(hp0[1]);
            float2 f10 = __half22float2(hp1[0]), f11 = __half22float2(hp1[1]);
            a0 = fmaf(x0, f00.x, fmaf(x1, f10.x, a0));
            a1 = fmaf(x0, f00.y, fmaf(x1, f10.y, a1));
            a2 = fmaf(x0, f01.x, fmaf(x1, f11.x, a2));
            a3 = fmaf(x0, f01.y, fmaf(x1, f11.y, a3));
        }
        for (; e < len; ++e) {
            int se = __shfl(s, e);
            float xe = __shfl(ex, grp | e);
            float2 hv = *(const float2*)(h + (size_t)se * 256 + l * 4);
            __half2* hp = (__half2*)&hv;
            float2 f0 = __half22float2(hp[0]), f1 = __half22float2(hp[1]);
            a0 = fmaf(xe, f0.x, a0);
            a1 = fmaf(xe, f0.y, a1);
            a2 = fmaf(xe, f1.x, a2);
            a3 = fmaf(xe, f1.y, a3);
        }
    }
    float inv = 1.f / (den + 1e-16f);
    float2 st;
    __half2* sp = (__half2*)&st;
    sp[0] = __floats2half2_rn(silu_f(a0 * inv), silu_f(a1 * inv));
    sp[1] = __floats2half2_rn(silu_f(a2 * inv), silu_f(a3 * inv));
    *(float2*)(out + (size_t)d * 256 + l * 4) = st;
}

// ---------- fused MLP head: two MFMA stages (64->64->32->1) + energy reduction ----------
// block = 64 nodes, channel loop inside. Layer1: in[64xFIN=64] x W1 -> t1 (LDS fp16).
// Layer2: t1[64x64] x W2[c] -> t2; silu.w3 dot; 16-lane reduce; y accumulated over c.
__global__ __launch_bounds__(256) void mlp_fused_kernel(const __half* __restrict__ in,
                                                        const float* __restrict__ W1,
                                                        const float* __restrict__ W2,
                                                        const float* __restrict__ W3,
                                                        const int* __restrict__ bat,
                                                        float* __restrict__ out) {
    constexpr int WSH = 72;           // 64+8 halves
    __shared__ __half W1t[64 * WSH];  // [o][swz k] for current channel
    __shared__ __half inl[64 * WSH];  // [node][k]
    __shared__ __half t1l[64 * WSH];  // [node][o] (linear)
    __shared__ __half W2t[NCH][32 * WSH];  // all channels, staged once
    __shared__ float w3l[NCH * 32];
    __shared__ float ynode[64];
    const int tid = threadIdx.x;
    const int n0 = blockIdx.x * 64;
    const int w = tid >> 6;
    const int l = tid & 63;
    const int col = l & 15;
    const int g = l >> 4;

    // stage W2 (all channels) transposed + octet-swizzled (OM=7)
    for (int i = tid; i < NCH * 32 * 32; i += 256) {
        int cc = i >> 10, rem = i & 1023;
        int kp = rem >> 5, o2 = rem & 31;
        int k = kp * 2;
        float a = W2[cc * 2048 + k * 32 + o2];
        float b = W2[cc * 2048 + (k + 1) * 32 + o2];
        int pos = ((((k >> 3) ^ (o2 >> 2)) & 7) << 3) | (k & 7);
        *(__half2*)(&W2t[cc][o2 * WSH + pos]) = __floats2half2_rn(a, b);
    }
    if (tid < NCH * 32) w3l[tid] = W3[tid];

    float yacc[4] = {0.f, 0.f, 0.f, 0.f};

    for (int c = 0; c < NCH; ++c) {
        __syncthreads();  // protect W1t/inl overwrite (and cover W2t on first iter)
        // stage W1[c] transposed + swizzled
        for (int i = tid; i < 32 * 64; i += 256) {
            int kp = i >> 6, oo = i & 63;
            int k = kp * 2;
            float a = W1[c * 4096 + k * 64 + oo];
            float b = W1[c * 4096 + (k + 1) * 64 + oo];
            int pos = ((((k >> 3) ^ (oo >> 2)) & 7) << 3) | (k & 7);
            *(__half2*)(&W1t[oo * WSH + pos]) = __floats2half2_rn(a, b);
        }
        // stage input rows (fp16, 8-chunks, clamped)
        for (int i = tid; i < 64 * 8; i += 256) {
            int nl = i >> 3, ch = i & 7;
            int node = min(n0 + nl, N_ATOMS - 1);
            *(float4*)(inl + nl * WSH + ch * 8) =
                *(const float4*)(in + (size_t)node * 256 + c * 64 + ch * 8);
        }
        __syncthreads();

        // layer 1 MFMA: [64x64] x [64x64]
        f32x4v acc[4];
#pragma unroll
        for (int t = 0; t < 4; ++t) acc[t] = (f32x4v){0.f, 0.f, 0.f, 0.f};
        const __half* arow = inl + (w * 16 + col) * WSH + g * 8;
#pragma unroll
        for (int it = 0; it < 2; ++it) {
            half8v af = ld_frag(arow + it * 32);
            int J = it * 4 + g;
#pragma unroll
            for (int t = 0; t < 4; ++t) {
                int oo = 16 * t + col;
                half8v bf = ld_frag(W1t + oo * WSH + (((J ^ (oo >> 2)) & 7) << 3));
                acc[t] = __builtin_amdgcn_mfma_f32_16x16x32_f16(af, bf, acc[t], 0, 0, 0);
            }
        }
        // silu(t1) -> LDS (wave-own rows; in-wave LDS ordering via lgkmcnt)
#pragma unroll
        for (int t = 0; t < 4; ++t)
#pragma unroll
            for (int r = 0; r < 4; ++r)
                t1l[(w * 16 + g * 4 + r) * WSH + 16 * t + col] = __float2half(silu_f(acc[t][r]));

        // layer 2 MFMA: [64x64] x [64x32] (A linear, B swizzled)
        f32x4v acc2[2];
        acc2[0] = (f32x4v){0.f, 0.f, 0.f, 0.f};
        acc2[1] = (f32x4v){0.f, 0.f, 0.f, 0.f};
        const __half* arow2 = t1l + (w * 16 + col) * WSH + g * 8;
#pragma unroll
        for (int it = 0; it < 2; ++it) {
            half8v af = ld_frag(arow2 + it * 32);
            int J = it * 4 + g;
#pragma unroll
            for (int t = 0; t < 2; ++t) {
                int o2 = 16 * t + col;
                half8v bf = ld_frag(&W2t[c][o2 * WSH + (((J ^ (o2 >> 2)) & 7) << 3)]);
                acc2[t] = __builtin_amdgcn_mfma_f32_16x16x32_f16(af, bf, acc2[t], 0, 0, 0);
            }
        }
        // layer 3: y += sum_o2 silu(t2[o2]) * w3[o2]; reduce over 16 col-lanes
        float w3a = w3l[c * 32 + col], w3b = w3l[c * 32 + 16 + col];
#pragma unroll
        for (int r = 0; r < 4; ++r) {
            float p = silu_f(acc2[0][r]) * w3a + silu_f(acc2[1][r]) * w3b;
#pragma unroll
            for (int off = 1; off < 16; off <<= 1) p += __shfl_xor(p, off);
            yacc[r] += p;
        }
    }

    if (col == 0) {
#pragma unroll
        for (int r = 0; r < 4; ++r) ynode[w * 16 + g * 4 + r] = yacc[r];
    }
    __syncthreads();
    if (tid < 64) {  // wave 0: segmented energy reduction over 64 nodes
        int node = n0 + tid;
        bool act = node < N_ATOMS;
        float val = act ? ynode[tid] * 0.025f : 0.f;  // /sqrt(4)/20
        int b = act ? bat[min(node, N_ATOMS - 1)] : 0;
        unsigned long long rem = __ballot(act);
        while (rem) {
            int lead = (int)__ffsll(rem) - 1;
            int bl = __shfl(b, lead);
            bool mine = act && (b == bl);
            float t = mine ? val : 0.f;
#pragma unroll
            for (int off = 32; off; off >>= 1) t += __shfl_xor(t, off);
            if (tid == lead) atomicAdd(out + bl, t);
            rem &= ~__ballot(mine);
        }
    }
}

extern "C" void kernel_launch(void* const* d_in, const int* in_sizes, int n_in,
                              void* d_out, int out_size, void* d_ws, size_t ws_size,
                              hipStream_t stream) {
    const float* x     = (const float*)d_in[0];
    const int*   ei    = (const int*)d_in[1];
    const int*   bat   = (const int*)d_in[2];
    const float* gamma = (const float*)d_in[3];
    const float* beta  = (const float*)d_in[4];
    const float* Wc1   = (const float*)d_in[5];
    const float* as1   = (const float*)d_in[6];
    const float* ad1   = (const float*)d_in[7];
    const float* Wc2   = (const float*)d_in[8];
    const float* as2   = (const float*)d_in[9];
    const float* ad2   = (const float*)d_in[10];
    const float* Wn1   = (const float*)d_in[11];
    const float* Wn2   = (const float*)d_in[12];
    const float* Wout  = (const float*)d_in[13];
    float* out = (float*)d_out;

    // workspace layout (floats)
    float* A    = (float*)d_ws;            // C1h/C2h fp16 conv outs
    float* B    = A + 10240000;            // Bh fp16 proj h
    float* es   = B + 5120000;             // 80k
    float* ed   = es + 80000;              // 80k
    int* rowp   = (int*)(ed + 80000);      // 20001 (pad 20004)
    int* cnt    = rowp + 20004;            // 20000
    int* fillc  = cnt + 20000;             // 20000
    int* csr    = fillc + 20000;           // 400000
    int* bsum   = csr + 400000;            // 128
    int* boff   = bsum + 128;              // 128
    __half* C1h = (__half*)A;              // conv1 out (silu'd, fp16) [N,256]
    __half* C2h = (__half*)(A + 2560000);  // conv2 out (silu'd, fp16) [N,256]
    __half* Bh  = (__half*)B;              // proj h (fp16) for gathers

    dim3 blk(256);
    const int NB = (N_ATOMS + 255) / 256;   // 79
    const int NT64 = (N_ATOMS + 63) / 64;   // 313

    // ---- CSR build (graph is shared by both convs) ----
    fill_kernel<<<80, blk, 0, stream>>>((float*)cnt, 40000, 0.f);  // cnt + fillc (adjacent)
    hist_kernel<<<(N_EDGES + 255) / 256, blk, 0, stream>>>(ei, cnt, N_EDGES);
    scan_l1_kernel<<<NB, blk, 0, stream>>>(cnt, rowp, bsum, N_ATOMS);
    scan_l2_kernel<<<1, blk, 0, stream>>>(bsum, boff, rowp + N_ATOMS, NB, out);
    scan_l3_kernel<<<NB, blk, 0, stream>>>(rowp, boff, N_ATOMS);
    scatter_kernel<<<(N_EDGES + 255) / 256, blk, 0, stream>>>(ei, rowp, fillc, csr, N_EDGES);

    // ---- conv1 (LN fused into proj staging; h fp16) ----
    proj_kernel<128, NCH * F_IN, false, true, true, false, true>
        <<<dim3(NT64, NCH), blk, 0, stream>>>(x, gamma, beta, Wc1, as1, ad1, Bh, es, ed);
    gat_gather_kernel<<<N_ATOMS / 4, blk, 0, stream>>>(rowp, csr, es, ed, Bh, C1h);

    // ---- conv2 (fp16 input staging) ----
    proj_kernel<64, 256, true, false, true, false, true>
        <<<dim3(NT64, NCH), blk, 0, stream>>>(C1h, gamma, beta, Wc2, as2, ad2, Bh, es, ed);
    gat_gather_kernel<<<N_ATOMS / 4, blk, 0, stream>>>(rowp, csr, es, ed, Bh, C2h);

    // ---- fused MLP head: two MFMA stages + energy reduction ----
    mlp_fused_kernel<<<NT64, blk, 0, stream>>>(C2h, Wn1, Wn2, Wout, bat, out);
}

// Round 20
// 174.998 us; speedup vs baseline: 1.3164x; 1.0642x over previous
//
#include <hip/hip_runtime.h>
#include <hip/hip_bf16.h>
#include <hip/hip_fp16.h>

// Problem constants (match reference)
#define N_ATOMS 20000
#define N_EDGES 400000
#define NCH 4
#define F_IN 128
#define S_OUT 32

// ---------- helpers ----------
__device__ __forceinline__ float silu_f(float v) { return v / (1.f + __expf(-v)); }

typedef _Float16 half8v __attribute__((ext_vector_type(8)));
typedef float f32x4v __attribute__((ext_vector_type(4)));

__device__ __forceinline__ half8v ld_frag(const __half* p) {
    union { float4 f; half8v h; } u;
    u.f = *(const float4*)p;
    return u.h;
}

__device__ __forceinline__ int wave_iscan(int v, int l) {
#pragma unroll
    for (int off = 1; off < 64; off <<= 1) {
        int t = __shfl_up(v, off);
        if (l >= off) v += t;
    }
    return v;
}

// ---------- fill ----------
__global__ void fill_kernel(float* __restrict__ p, int n, float v) {
    int i = blockIdx.x * blockDim.x + threadIdx.x;
    int stride = gridDim.x * blockDim.x;
    for (; i < n; i += stride) p[i] = v;
}

// ---------- CSR build: histogram -> hierarchical scan -> scatter ----------
__global__ void hist_kernel(const int* __restrict__ ei, int* __restrict__ cnt, int E) {
    int e = blockIdx.x * 256 + threadIdx.x;
    if (e < E) atomicAdd(&cnt[ei[E + e]], 1);
}

__global__ __launch_bounds__(256) void scan_l1_kernel(const int* __restrict__ cnt,
                                                      int* __restrict__ rowp,
                                                      int* __restrict__ bsum, int n) {
    int i = blockIdx.x * 256 + threadIdx.x;
    int l = threadIdx.x & 63, w = threadIdx.x >> 6;
    int v = (i < n) ? cnt[i] : 0;
    int incl = wave_iscan(v, l);
    __shared__ int wsum[4];
    if (l == 63) wsum[w] = incl;
    __syncthreads();
    int add = 0;
#pragma unroll
    for (int j = 0; j < 4; ++j) add += (j < w) ? wsum[j] : 0;
    if (i < n) rowp[i] = add + incl - v;
    if (threadIdx.x == 255) bsum[blockIdx.x] = add + incl;
}

__global__ __launch_bounds__(256) void scan_l2_kernel(const int* __restrict__ bsum,
                                                      int* __restrict__ boff,
                                                      int* __restrict__ rowp_n, int nb,
                                                      float* __restrict__ out_zero) {
    int i = threadIdx.x;
    if (i < S_OUT) out_zero[i] = 0.f;  // fused energies zero-init
    int l = i & 63, w = i >> 6;
    int v = (i < nb) ? bsum[i] : 0;
    int incl = wave_iscan(v, l);
    __shared__ int wsum[4];
    if (l == 63) wsum[w] = incl;
    __syncthreads();
    int add = 0;
#pragma unroll
    for (int j = 0; j < 4; ++j) add += (j < w) ? wsum[j] : 0;
    if (i < nb) boff[i] = add + incl - v;
    if (i == nb - 1) *rowp_n = add + incl;
}

__global__ __launch_bounds__(256) void scan_l3_kernel(int* __restrict__ rowp,
                                                      const int* __restrict__ boff, int n) {
    int i = blockIdx.x * 256 + threadIdx.x;
    if (i < n) rowp[i] += boff[blockIdx.x];
}

__global__ void scatter_kernel(const int* __restrict__ ei, const int* __restrict__ rowp,
                               int* __restrict__ fill, int* __restrict__ csr_src, int E) {
    int e = blockIdx.x * 256 + threadIdx.x;
    if (e < E) {
        int d = ei[E + e];
        int pos = rowp[d] + atomicAdd(&fill[d], 1);
        csr_src[pos] = ei[e];
    }
}

// ---------- projection via MFMA: block = 64 nodes x 64 outputs, c = blockIdx.y ----------
template <int FIN, int IN_STRIDE, bool IN_HALF, bool LN, bool ATT, bool SILU_OUT, bool OUT_HALF>
__global__ __launch_bounds__(256) void proj_kernel(const void* __restrict__ inv,
                                                   const float* __restrict__ gamma,
                                                   const float* __restrict__ beta,
                                                   const float* __restrict__ W,
                                                   const float* __restrict__ a_src,
                                                   const float* __restrict__ a_dst,
                                                   void* __restrict__ outv,
                                                   float* __restrict__ es,
                                                   float* __restrict__ ed) {
    constexpr int OCT = FIN / 8;      // octets per row
    constexpr int OM = OCT - 1;
    constexpr int WSH = FIN + 8;      // halves stride (rows 16B-aligned)
    __shared__ __half Wt[64 * WSH];   // [o][store-swizzled k]
    __shared__ __half inl[64 * WSH];  // [node][k] linear
    const int tid = threadIdx.x;
    const int c = blockIdx.y;
    const int n0 = blockIdx.x * 64;
    const int w = tid >> 6;           // wave 0..3
    const int l = tid & 63;
    const int col = l & 15;           // MFMA row/col lane index
    const int g = l >> 4;             // k-octet group 0..3

    const float* __restrict__ Wc = W + c * (FIN * 64);
    for (int i = tid; i < (FIN / 2) * 64; i += 256) {
        int kp = i >> 6, oo = i & 63;
        int k = kp * 2;
        float w0 = Wc[(size_t)k * 64 + oo];
        float w1 = Wc[(size_t)(k + 1) * 64 + oo];
        int pos = ((((k >> 3) ^ (oo >> 2)) & OM) << 3) | (k & 7);
        *(__half2*)(&Wt[oo * WSH + pos]) = __floats2half2_rn(w0, w1);
    }
    if (IN_HALF) {
        const __half* __restrict__ inh = (const __half*)inv;
        for (int i = tid; i < 64 * (FIN / 8); i += 256) {
            int nl = i / (FIN / 8), ch = i % (FIN / 8);
            int node = min(n0 + nl, N_ATOMS - 1);
            *(float4*)(inl + nl * WSH + ch * 8) =
                *(const float4*)(inh + (size_t)node * IN_STRIDE + c * FIN + ch * 8);
        }
    } else {
        const float* __restrict__ inf = (const float*)inv;
        for (int i = tid; i < 64 * (FIN / 8); i += 256) {
            int nl = i / (FIN / 8), ch = i % (FIN / 8);
            int node = min(n0 + nl, N_ATOMS - 1);
            const float* src = inf + (size_t)node * IN_STRIDE + c * FIN + ch * 8;
            float4 a = *(const float4*)src;
            float4 b = *(const float4*)(src + 4);
            float4 st;
            __half2* sp = (__half2*)&st;
            sp[0] = __floats2half2_rn(a.x, a.y);
            sp[1] = __floats2half2_rn(a.z, a.w);
            sp[2] = __floats2half2_rn(b.x, b.y);
            sp[3] = __floats2half2_rn(b.z, b.w);
            *(float4*)(inl + nl * WSH + ch * 8) = st;
        }
    }
    __syncthreads();

    if (LN) {  // parallel LayerNorm: 4 rows/wave concurrently, 16-lane-group reduce
        int sub = l >> 4;      // row subgroup 0..3
        int l16 = l & 15;
        float gv[8], bv8[8];
#pragma unroll
        for (int j = 0; j < 8; ++j) {
            gv[j] = gamma[l16 * 8 + j];
            bv8[j] = beta[l16 * 8 + j];
        }
#pragma unroll
        for (int it = 0; it < 4; ++it) {
            int row = w * 16 + it * 4 + sub;
            __half* rp = inl + row * WSH + l16 * 8;
            float4 raw = *(const float4*)rp;
            __half2* hp = (__half2*)&raw;
            float v[8];
#pragma unroll
            for (int j = 0; j < 4; ++j) {
                float2 f = __half22float2(hp[j]);
                v[2 * j] = f.x;
                v[2 * j + 1] = f.y;
            }
            float s = 0.f, sq = 0.f;
#pragma unroll
            for (int j = 0; j < 8; ++j) { s += v[j]; sq += v[j] * v[j]; }
#pragma unroll
            for (int off = 1; off < 16; off <<= 1) {
                s += __shfl_xor(s, off);
                sq += __shfl_xor(sq, off);
            }
            float mu = s * (1.f / 128.f);
            float rs = rsqrtf(sq * (1.f / 128.f) - mu * mu + 1e-5f);
            float4 st;
            __half2* sp = (__half2*)&st;
#pragma unroll
            for (int j = 0; j < 4; ++j)
                sp[j] = __floats2half2_rn((v[2 * j] - mu) * rs * gv[2 * j] + bv8[2 * j],
                                          (v[2 * j + 1] - mu) * rs * gv[2 * j + 1] + bv8[2 * j + 1]);
            *(float4*)rp = st;
        }
        __syncthreads();
    }

    f32x4v acc[4];
#pragma unroll
    for (int t = 0; t < 4; ++t) acc[t] = (f32x4v){0.f, 0.f, 0.f, 0.f};

    const __half* arow = inl + (w * 16 + col) * WSH + g * 8;
#pragma unroll
    for (int it = 0; it < FIN / 32; ++it) {
        half8v af = ld_frag(arow + it * 32);
        int J = it * 4 + g;
#pragma unroll
        for (int t = 0; t < 4; ++t) {
            int oo = 16 * t + col;
            half8v bf = ld_frag(Wt + oo * WSH + (((J ^ (oo >> 2)) & OM) << 3));
            acc[t] = __builtin_amdgcn_mfma_f32_16x16x32_f16(af, bf, acc[t], 0, 0, 0);
        }
    }

    // epilogue: D layout col=lane&15, row=(lane>>4)*4+reg
    float av[4], bv[4];
    if (ATT) {
#pragma unroll
        for (int t = 0; t < 4; ++t) {
            av[t] = a_src[c * 64 + 16 * t + col];
            bv[t] = a_dst[c * 64 + 16 * t + col];
        }
    }
#pragma unroll
    for (int r = 0; r < 4; ++r) {
        int node = n0 + w * 16 + g * 4 + r;
        bool valid = node < N_ATOMS;
        if (valid) {
#pragma unroll
            for (int t = 0; t < 4; ++t) {
                float o = acc[t][r];
                if (SILU_OUT) o = silu_f(o);
                if (OUT_HALF)
                    ((__half*)outv)[(size_t)node * 256 + c * 64 + 16 * t + col] = __float2half(o);
                else
                    ((float*)outv)[(size_t)node * 256 + c * 64 + 16 * t + col] = o;
            }
        }
        if (ATT) {
            float ps = 0.f, pd = 0.f;
#pragma unroll
            for (int t = 0; t < 4; ++t) {
                ps = fmaf(acc[t][r], av[t], ps);
                pd = fmaf(acc[t][r], bv[t], pd);
            }
#pragma unroll
            for (int off = 1; off < 16; off <<= 1) {
                ps += __shfl_xor(ps, off);
                pd += __shfl_xor(pd, off);
            }
            if (col == 0 && valid) { es[node * NCH + c] = ps; ed[node * NCH + c] = pd; }
        }
    }
}

// ---------- fused GAT aggregation: ONE wave per dst, all 4 channels ----------
__global__ __launch_bounds__(256) void gat_gather_kernel(const int* __restrict__ rowp,
                                                         const int* __restrict__ csr_src,
                                                         const float* __restrict__ es,
                                                         const float* __restrict__ ed,
                                                         const __half* __restrict__ h,
                                                         __half* __restrict__ out) {
    int l = threadIdx.x & 63;
    int d = blockIdx.x * 4 + (threadIdx.x >> 6);
    int c = l >> 4, q = l & 15;
    int r0 = rowp[d], r1 = rowp[d + 1];
    float edc = ed[d * NCH + c];
    float m = -1e30f, den = 0.f;
    float a0 = 0.f, a1 = 0.f, a2 = 0.f, a3 = 0.f;
    int grp = l & 48;

    for (int base = r0; base < r1; base += 16) {
        int len = min(16, r1 - base);
        float logit = -1e30f;
        int s = 0;
        if (q < len) {
            s = csr_src[base + q];
            float v = es[s * NCH + c] + edc;
            logit = v >= 0.f ? v : 0.2f * v;
        }
        float cm = logit;
#pragma unroll
        for (int off = 8; off; off >>= 1) cm = fmaxf(cm, __shfl_xor(cm, off));
        float nm = fmaxf(m, cm);
        float resc = __expf(m - nm);
        float ex = (q < len) ? __expf(logit - nm) : 0.f;
        float cs = ex;
#pragma unroll
        for (int off = 8; off; off >>= 1) cs += __shfl_xor(cs, off);
        den = den * resc + cs;
        a0 *= resc; a1 *= resc; a2 *= resc; a3 *= resc;
        m = nm;
        int e = 0;
        for (; e + 4 <= len; e += 4) {  // 4 h-row loads in flight
            int s0 = __shfl(s, e),     s1 = __shfl(s, e + 1);
            int s2 = __shfl(s, e + 2), s3 = __shfl(s, e + 3);
            float x0 = __shfl(ex, grp | e),       x1 = __shfl(ex, grp | (e + 1));
            float x2 = __shfl(ex, grp | (e + 2)), x3 = __shfl(ex, grp | (e + 3));
            float2 hv0 = *(const float2*)(h + (size_t)s0 * 256 + l * 4);
            float2 hv1 = *(const float2*)(h + (size_t)s1 * 256 + l * 4);
            float2 hv2 = *(const float2*)(h + (size_t)s2 * 256 + l * 4);
            float2 hv3 = *(const float2*)(h + (size_t)s3 * 256 + l * 4);
            __half2* p0 = (__half2*)&hv0;
            __half2* p1 = (__half2*)&hv1;
            __half2* p2 = (__half2*)&hv2;
            __half2* p3 = (__half2*)&hv3;
            float2 f00 = __half22float2(p0[0]), f01 = __half22float2(p0[1]);
            float2 f10 = __half22float2(p1[0]), f11 = __half22float2(p1[1]);
            float2 f20 = __half22float2(p2[0]), f21 = __half22float2(p2[1]);
            float2 f30 = __half22float2(p3[0]), f31 = __half22float2(p3[1]);
            a0 = fmaf(x0, f00.x, fmaf(x1, f10.x, fmaf(x2, f20.x, fmaf(x3, f30.x, a0))));
            a1 = fmaf(x0, f00.y, fmaf(x1, f10.y, fmaf(x2, f20.y, fmaf(x3, f30.y, a1))));
            a2 = fmaf(x0, f01.x, fmaf(x1, f11.x, fmaf(x2, f21.x, fmaf(x3, f31.x, a2))));
            a3 = fmaf(x0, f01.y, fmaf(x1, f11.y, fmaf(x2, f21.y, fmaf(x3, f31.y, a3))));
        }
        for (; e < len; ++e) {
            int se = __shfl(s, e);
            float xe = __shfl(ex, grp | e);
            float2 hv = *(const float2*)(h + (size_t)se * 256 + l * 4);
            __half2* hp = (__half2*)&hv;
            float2 f0 = __half22float2(hp[0]), f1 = __half22float2(hp[1]);
            a0 = fmaf(xe, f0.x, a0);
            a1 = fmaf(xe, f0.y, a1);
            a2 = fmaf(xe, f1.x, a2);
            a3 = fmaf(xe, f1.y, a3);
        }
    }
    float inv = 1.f / (den + 1e-16f);
    float2 st;
    __half2* sp = (__half2*)&st;
    sp[0] = __floats2half2_rn(silu_f(a0 * inv), silu_f(a1 * inv));
    sp[1] = __floats2half2_rn(silu_f(a2 * inv), silu_f(a3 * inv));
    *(float2*)(out + (size_t)d * 256 + l * 4) = st;
}

// ---------- fused MLP head: two MFMA stages (64->64->32->1) + energy reduction ----------
__global__ __launch_bounds__(256) void mlp_fused_kernel(const __half* __restrict__ in,
                                                        const float* __restrict__ W1,
                                                        const float* __restrict__ W2,
                                                        const float* __restrict__ W3,
                                                        const int* __restrict__ bat,
                                                        float* __restrict__ out) {
    constexpr int WSH = 72;           // 64+8 halves
    __shared__ __half W1t[64 * WSH];  // [o][swz k] for current channel
    __shared__ __half inl[64 * WSH];  // [node][k]
    __shared__ __half t1l[64 * WSH];  // [node][o] (linear)
    __shared__ __half W2t[NCH][32 * WSH];  // all channels, staged once
    __shared__ float w3l[NCH * 32];
    __shared__ float ynode[64];
    const int tid = threadIdx.x;
    const int n0 = blockIdx.x * 64;
    const int w = tid >> 6;
    const int l = tid & 63;
    const int col = l & 15;
    const int g = l >> 4;

    for (int i = tid; i < NCH * 32 * 32; i += 256) {
        int cc = i >> 10, rem = i & 1023;
        int kp = rem >> 5, o2 = rem & 31;
        int k = kp * 2;
        float a = W2[cc * 2048 + k * 32 + o2];
        float b = W2[cc * 2048 + (k + 1) * 32 + o2];
        int pos = ((((k >> 3) ^ (o2 >> 2)) & 7) << 3) | (k & 7);
        *(__half2*)(&W2t[cc][o2 * WSH + pos]) = __floats2half2_rn(a, b);
    }
    if (tid < NCH * 32) w3l[tid] = W3[tid];

    float yacc[4] = {0.f, 0.f, 0.f, 0.f};

    for (int c = 0; c < NCH; ++c) {
        __syncthreads();
        for (int i = tid; i < 32 * 64; i += 256) {
            int kp = i >> 6, oo = i & 63;
            int k = kp * 2;
            float a = W1[c * 4096 + k * 64 + oo];
            float b = W1[c * 4096 + (k + 1) * 64 + oo];
            int pos = ((((k >> 3) ^ (oo >> 2)) & 7) << 3) | (k & 7);
            *(__half2*)(&W1t[oo * WSH + pos]) = __floats2half2_rn(a, b);
        }
        for (int i = tid; i < 64 * 8; i += 256) {
            int nl = i >> 3, ch = i & 7;
            int node = min(n0 + nl, N_ATOMS - 1);
            *(float4*)(inl + nl * WSH + ch * 8) =
                *(const float4*)(in + (size_t)node * 256 + c * 64 + ch * 8);
        }
        __syncthreads();

        f32x4v acc[4];
#pragma unroll
        for (int t = 0; t < 4; ++t) acc[t] = (f32x4v){0.f, 0.f, 0.f, 0.f};
        const __half* arow = inl + (w * 16 + col) * WSH + g * 8;
#pragma unroll
        for (int it = 0; it < 2; ++it) {
            half8v af = ld_frag(arow + it * 32);
            int J = it * 4 + g;
#pragma unroll
            for (int t = 0; t < 4; ++t) {
                int oo = 16 * t + col;
                half8v bf = ld_frag(W1t + oo * WSH + (((J ^ (oo >> 2)) & 7) << 3));
                acc[t] = __builtin_amdgcn_mfma_f32_16x16x32_f16(af, bf, acc[t], 0, 0, 0);
            }
        }
#pragma unroll
        for (int t = 0; t < 4; ++t)
#pragma unroll
            for (int r = 0; r < 4; ++r)
                t1l[(w * 16 + g * 4 + r) * WSH + 16 * t + col] = __float2half(silu_f(acc[t][r]));

        f32x4v acc2[2];
        acc2[0] = (f32x4v){0.f, 0.f, 0.f, 0.f};
        acc2[1] = (f32x4v){0.f, 0.f, 0.f, 0.f};
        const __half* arow2 = t1l + (w * 16 + col) * WSH + g * 8;
#pragma unroll
        for (int it = 0; it < 2; ++it) {
            half8v af = ld_frag(arow2 + it * 32);
            int J = it * 4 + g;
#pragma unroll
            for (int t = 0; t < 2; ++t) {
                int o2 = 16 * t + col;
                half8v bf = ld_frag(&W2t[c][o2 * WSH + (((J ^ (o2 >> 2)) & 7) << 3)]);
                acc2[t] = __builtin_amdgcn_mfma_f32_16x16x32_f16(af, bf, acc2[t], 0, 0, 0);
            }
        }
        float w3a = w3l[c * 32 + col], w3b = w3l[c * 32 + 16 + col];
#pragma unroll
        for (int r = 0; r < 4; ++r) {
            float p = silu_f(acc2[0][r]) * w3a + silu_f(acc2[1][r]) * w3b;
#pragma unroll
            for (int off = 1; off < 16; off <<= 1) p += __shfl_xor(p, off);
            yacc[r] += p;
        }
    }

    if (col == 0) {
#pragma unroll
        for (int r = 0; r < 4; ++r) ynode[w * 16 + g * 4 + r] = yacc[r];
    }
    __syncthreads();
    if (tid < 64) {
        int node = n0 + tid;
        bool act = node < N_ATOMS;
        float val = act ? ynode[tid] * 0.025f : 0.f;  // /sqrt(4)/20
        int b = act ? bat[min(node, N_ATOMS - 1)] : 0;
        unsigned long long rem = __ballot(act);
        while (rem) {
            int lead = (int)__ffsll(rem) - 1;
            int bl = __shfl(b, lead);
            bool mine = act && (b == bl);
            float t = mine ? val : 0.f;
#pragma unroll
            for (int off = 32; off; off >>= 1) t += __shfl_xor(t, off);
            if (tid == lead) atomicAdd(out + bl, t);
            rem &= ~__ballot(mine);
        }
    }
}

extern "C" void kernel_launch(void* const* d_in, const int* in_sizes, int n_in,
                              void* d_out, int out_size, void* d_ws, size_t ws_size,
                              hipStream_t stream) {
    const float* x     = (const float*)d_in[0];
    const int*   ei    = (const int*)d_in[1];
    const int*   bat   = (const int*)d_in[2];
    const float* gamma = (const float*)d_in[3];
    const float* beta  = (const float*)d_in[4];
    const float* Wc1   = (const float*)d_in[5];
    const float* as1   = (const float*)d_in[6];
    const float* ad1   = (const float*)d_in[7];
    const float* Wc2   = (const float*)d_in[8];
    const float* as2   = (const float*)d_in[9];
    const float* ad2   = (const float*)d_in[10];
    const float* Wn1   = (const float*)d_in[11];
    const float* Wn2   = (const float*)d_in[12];
    const float* Wout  = (const float*)d_in[13];
    float* out = (float*)d_out;

    // workspace layout (floats)
    float* A    = (float*)d_ws;            // C1h/C2h fp16 conv outs
    float* B    = A + 10240000;            // Bh fp16 proj h
    float* es   = B + 5120000;             // 80k
    float* ed   = es + 80000;              // 80k
    int* rowp   = (int*)(ed + 80000);      // 20001 (pad 20004)
    int* cnt    = rowp + 20004;            // 20000
    int* fillc  = cnt + 20000;             // 20000
    int* csr    = fillc + 20000;           // 400000
    int* bsum   = csr + 400000;            // 128
    int* boff   = bsum + 128;              // 128
    __half* C1h = (__half*)A;              // conv1 out (silu'd, fp16) [N,256]
    __half* C2h = (__half*)(A + 2560000);  // conv2 out (silu'd, fp16) [N,256]
    __half* Bh  = (__half*)B;              // proj h (fp16) for gathers

    dim3 blk(256);
    const int NB = (N_ATOMS + 255) / 256;   // 79
    const int NT64 = (N_ATOMS + 63) / 64;   // 313

    // ---- CSR build (graph is shared by both convs) ----
    fill_kernel<<<80, blk, 0, stream>>>((float*)cnt, 40000, 0.f);  // cnt + fillc (adjacent)
    hist_kernel<<<(N_EDGES + 255) / 256, blk, 0, stream>>>(ei, cnt, N_EDGES);
    scan_l1_kernel<<<NB, blk, 0, stream>>>(cnt, rowp, bsum, N_ATOMS);
    scan_l2_kernel<<<1, blk, 0, stream>>>(bsum, boff, rowp + N_ATOMS, NB, out);
    scan_l3_kernel<<<NB, blk, 0, stream>>>(rowp, boff, N_ATOMS);
    scatter_kernel<<<(N_EDGES + 255) / 256, blk, 0, stream>>>(ei, rowp, fillc, csr, N_EDGES);

    // ---- conv1 (LN fused into proj staging; h fp16) ----
    proj_kernel<128, NCH * F_IN, false, true, true, false, true>
        <<<dim3(NT64, NCH), blk, 0, stream>>>(x, gamma, beta, Wc1, as1, ad1, Bh, es, ed);
    gat_gather_kernel<<<N_ATOMS / 4, blk, 0, stream>>>(rowp, csr, es, ed, Bh, C1h);

    // ---- conv2 (fp16 input staging) ----
    proj_kernel<64, 256, true, false, true, false, true>
        <<<dim3(NT64, NCH), blk, 0, stream>>>(C1h, gamma, beta, Wc2, as2, ad2, Bh, es, ed);
    gat_gather_kernel<<<N_ATOMS / 4, blk, 0, stream>>>(rowp, csr, es, ed, Bh, C2h);

    // ---- fused MLP head: two MFMA stages + energy reduction ----
    mlp_fused_kernel<<<NT64, blk, 0, stream>>>(C2h, Wn1, Wn2, Wout, bat, out);
}